// Round 1
// baseline (116.087 us; speedup 1.0000x reference)
//
#include <hip/hip_runtime.h>
#include <math.h>

#define NPTS   131072
#define BATCH  2
#define MBOX   128
#define NFPS   512
#define THREADS 256
#define KPT    8                    // points per thread per iteration
#define CHUNK  (THREADS * KPT)      // 2048
#define NITER  (NPTS / CHUNK)       // 64

__global__ __launch_bounds__(THREADS)
void roi_pool_kernel(const float* __restrict__ points,   // (N,4): [b, x, y, z]
                     const float* __restrict__ boxes,    // (B,M,7)
                     int* __restrict__ out_idx,          // (B,M,512)
                     int* __restrict__ out_num)          // (B,M)
{
    const int box  = blockIdx.x;          // b*M + m
    const int b    = box / MBOX;
    const int tid  = threadIdx.x;
    const int lane = tid & 63;
    const int wave = tid >> 6;

    // ---- box params (replicate reference fp32 arithmetic exactly) ----
    const float* bx = boxes + box * 7;
    const float cx = bx[0], cy = bx[1], cz = bx[2];
    const float bdx = bx[3], bdy = bx[4], bdz = bx[5], h = bx[6];
    // pcdet: dims = [bdy, bdx, bdz] + 2*POOL_EXTRA_WIDTH; heading = -(h + pi/2)
    const float hx = __fmul_rn(__fadd_rn(bdy, 2.0f), 0.5f);
    const float hy = __fmul_rn(__fadd_rn(bdx, 2.0f), 0.5f);
    const float hz = __fmul_rn(__fadd_rn(bdz, 2.0f), 0.5f);
    const float hp = -__fadd_rn(h, 1.5707963705062866f);  // fl32(pi/2)
    // correctly-rounded fp32 cos/sin via double
    const float c = (float)cos((double)hp);
    const float s = (float)sin((double)hp);

    __shared__ int s_wsum[THREADS / 64];

    int total = 0;
    const float4* p4 = (const float4*)points;
    const int boxbase = box * NFPS;

    for (int it = 0; it < NITER; ++it) {
        const int base = it * CHUNK + tid * KPT;
        unsigned mask = 0u;
        #pragma unroll
        for (int j = 0; j < KPT; ++j) {
            const float4 p = p4[base + j];
            const int   pb = (int)p.x;
            const float ddx = __fsub_rn(p.y, cx);
            const float ddy = __fsub_rn(p.z, cy);
            const float ddz = __fsub_rn(p.w, cz);
            const float lx = __fadd_rn(__fmul_rn(ddx, c), __fmul_rn(ddy, s));
            const float ly = __fadd_rn(__fmul_rn(-ddx, s), __fmul_rn(ddy, c));
            const bool inside = (fabsf(lx) <= hx) & (fabsf(ly) <= hy) &
                                (fabsf(ddz) <= hz) & (pb == b);
            mask |= (inside ? 1u : 0u) << j;
        }
        const int cnt = __popc(mask);

        // wave-level inclusive scan of per-thread counts
        int incl = cnt;
        #pragma unroll
        for (int off = 1; off < 64; off <<= 1) {
            const int v = __shfl_up(incl, off, 64);
            if (lane >= off) incl += v;
        }
        if (lane == 63) s_wsum[wave] = incl;
        __syncthreads();

        int wpre = 0, blocksum = 0;
        #pragma unroll
        for (int w = 0; w < THREADS / 64; ++w) {
            const int v = s_wsum[w];
            if (w < wave) wpre += v;
            blocksum += v;
        }

        // exclusive start position of this thread's inside points
        int pos = total + wpre + (incl - cnt);
        #pragma unroll
        for (int j = 0; j < KPT; ++j) {
            if (mask & (1u << j)) {
                if (pos < NFPS) out_idx[boxbase + pos] = base + j;
                ++pos;
            }
        }
        total += blocksum;
        __syncthreads();   // s_wsum reused next iteration
        if (total >= NFPS) break;   // uniform condition: pooled_num == 512
    }

    const int pn = total < NFPS ? total : NFPS;
    for (int k = pn + tid; k < NFPS; k += THREADS) out_idx[boxbase + k] = 0;
    if (tid == 0) out_num[box] = pn;
}

extern "C" void kernel_launch(void* const* d_in, const int* in_sizes, int n_in,
                              void* d_out, int out_size, void* d_ws, size_t ws_size,
                              hipStream_t stream) {
    const float* points = (const float*)d_in[0];   // (N,4) f32
    const float* boxes  = (const float*)d_in[1];   // (B,M,7) f32
    int* out_idx = (int*)d_out;                          // (B,M,512)
    int* out_num = (int*)d_out + BATCH * MBOX * NFPS;    // (B,M)

    roi_pool_kernel<<<BATCH * MBOX, THREADS, 0, stream>>>(points, boxes, out_idx, out_num);
}

// Round 2
// 26.093 us; speedup vs baseline: 4.4489x; 4.4489x over previous
//
#include <hip/hip_runtime.h>
#include <math.h>

#define NPTS   131072
#define BATCH  2
#define MBOX   128
#define NBOX   (BATCH * MBOX)       // 256
#define NFPS   512
#define THREADS 256

#define NSEG   64
#define SEGPTS 2048                 // points per segment
#define GRPBOX 16                   // boxes per phase-1 block
#define NGRP   (NBOX / GRPBOX)      // 16
#define DWPB   (NPTS / 32)          // 4096 bitmask dwords per box

// ---------------- Phase 1: build per-box inside-bitmask -----------------
__global__ __launch_bounds__(THREADS)
void roi_phase1(const float* __restrict__ points,   // (N,4): [b, x, y, z]
                const float* __restrict__ boxes,    // (B,M,7)
                unsigned* __restrict__ bits)        // (NBOX, DWPB)
{
    const int seg  = blockIdx.x;
    const int grp  = blockIdx.y;
    const int tid  = threadIdx.x;
    const int lane = tid & 63;
    const int w    = tid >> 6;

    // box params: [cx,cy,cz,hx,hy,hz,c,s] -- fp32 ops verbatim from the
    // passing round-1 kernel (boundary decisions must be bit-identical).
    __shared__ float s_box[GRPBOX][8];
    if (tid < GRPBOX) {
        const int box = grp * GRPBOX + tid;
        const float* bx = boxes + box * 7;
        const float bdx = bx[3], bdy = bx[4], bdz = bx[5], h = bx[6];
        s_box[tid][0] = bx[0];
        s_box[tid][1] = bx[1];
        s_box[tid][2] = bx[2];
        s_box[tid][3] = __fmul_rn(__fadd_rn(bdy, 2.0f), 0.5f);
        s_box[tid][4] = __fmul_rn(__fadd_rn(bdx, 2.0f), 0.5f);
        s_box[tid][5] = __fmul_rn(__fadd_rn(bdz, 2.0f), 0.5f);
        const float hp = -__fadd_rn(h, 1.5707963705062866f);  // fl32(pi/2)
        s_box[tid][6] = (float)cos((double)hp);
        s_box[tid][7] = (float)sin((double)hp);
    }
    __syncthreads();

    // load this thread's 8 consecutive points into registers (once)
    const float4* p4 = (const float4*)points;
    const int pbase = seg * SEGPTS + w * 512 + lane * 8;
    float4 p[8];
    #pragma unroll
    for (int j = 0; j < 8; ++j) p[j] = p4[pbase + j];

    #pragma unroll 1
    for (int bi = 0; bi < GRPBOX; ++bi) {
        const int box = grp * GRPBOX + bi;
        const int bB  = box >> 7;                 // box / MBOX
        const float cx = s_box[bi][0], cy = s_box[bi][1], cz = s_box[bi][2];
        const float hx = s_box[bi][3], hy = s_box[bi][4], hz = s_box[bi][5];
        const float c  = s_box[bi][6], s  = s_box[bi][7];

        unsigned m = 0u;
        #pragma unroll
        for (int j = 0; j < 8; ++j) {
            const int   pb  = (int)p[j].x;
            const float ddx = __fsub_rn(p[j].y, cx);
            const float ddy = __fsub_rn(p[j].z, cy);
            const float ddz = __fsub_rn(p[j].w, cz);
            const float lx  = __fadd_rn(__fmul_rn(ddx, c), __fmul_rn(ddy, s));
            const float ly  = __fadd_rn(__fmul_rn(-ddx, s), __fmul_rn(ddy, c));
            const bool inside = (fabsf(lx) <= hx) & (fabsf(ly) <= hy) &
                                (fabsf(ddz) <= hz) & (pb == bB);
            m |= (inside ? 1u : 0u) << j;
        }
        // pack 4 lanes' bytes into one dword on lanes where lane%4 == 0
        const unsigned v1 = __shfl_down(m, 1, 64);
        const unsigned v2 = __shfl_down(m, 2, 64);
        const unsigned v3 = __shfl_down(m, 3, 64);
        if ((lane & 3) == 0) {
            const unsigned dword = m | (v1 << 8) | (v2 << 16) | (v3 << 24);
            bits[box * DWPB + seg * 64 + w * 16 + (lane >> 2)] = dword;
        }
    }
}

// ------------- Phase 2: ordered compaction of the bitmask ---------------
__global__ __launch_bounds__(THREADS)
void roi_phase2(const unsigned* __restrict__ bits,  // (NBOX, DWPB)
                int* __restrict__ out_idx,          // (NBOX, 512)
                int* __restrict__ out_num)          // (NBOX)
{
    const int box  = blockIdx.x;
    const int tid  = threadIdx.x;
    const int lane = tid & 63;
    const int w    = tid >> 6;

    __shared__ int s_wsum[THREADS / 64];

    // thread t owns dwords [t*16, t*16+16) = points [t*512, (t+1)*512)
    unsigned v[16];
    const uint4* bp = (const uint4*)(bits + box * DWPB + tid * 16);
    #pragma unroll
    for (int i = 0; i < 4; ++i) {
        const uint4 q = bp[i];
        v[4*i + 0] = q.x; v[4*i + 1] = q.y; v[4*i + 2] = q.z; v[4*i + 3] = q.w;
    }
    int cnt = 0;
    #pragma unroll
    for (int i = 0; i < 16; ++i) cnt += __popc(v[i]);

    // wave inclusive scan
    int incl = cnt;
    #pragma unroll
    for (int off = 1; off < 64; off <<= 1) {
        const int x = __shfl_up(incl, off, 64);
        if (lane >= off) incl += x;
    }
    if (lane == 63) s_wsum[w] = incl;
    __syncthreads();

    int wpre = 0, total = 0;
    #pragma unroll
    for (int ww = 0; ww < THREADS / 64; ++ww) {
        const int x = s_wsum[ww];
        if (ww < w) wpre += x;
        total += x;
    }
    int pos = wpre + (incl - cnt);
    const int pn = total < NFPS ? total : NFPS;

    // zero-fill tail [pn, 512) -- disjoint from emitted [0, pn)
    const int obase = box * NFPS;
    for (int k = tid; k < NFPS; k += THREADS)
        if (k >= pn) out_idx[obase + k] = 0;

    // emit this thread's set bits in order
    const int pt0 = tid * 512;
    #pragma unroll
    for (int i = 0; i < 16; ++i) {
        unsigned x = v[i];
        while (x) {
            const int b = __ffs(x) - 1;
            if (pos < NFPS) out_idx[obase + pos] = pt0 + i * 32 + b;
            ++pos;
            x &= x - 1;
        }
    }
    if (tid == 0) out_num[box] = pn;
}

extern "C" void kernel_launch(void* const* d_in, const int* in_sizes, int n_in,
                              void* d_out, int out_size, void* d_ws, size_t ws_size,
                              hipStream_t stream) {
    const float* points = (const float*)d_in[0];   // (N,4) f32
    const float* boxes  = (const float*)d_in[1];   // (B,M,7) f32
    int* out_idx = (int*)d_out;                    // (B,M,512)
    int* out_num = (int*)d_out + NBOX * NFPS;      // (B,M)
    unsigned* bits = (unsigned*)d_ws;              // NBOX * DWPB dwords = 4 MB

    roi_phase1<<<dim3(NSEG, NGRP), THREADS, 0, stream>>>(points, boxes, bits);
    roi_phase2<<<NBOX, THREADS, 0, stream>>>(bits, out_idx, out_num);
}